// Round 5
// baseline (848.339 us; speedup 1.0000x reference)
//
#include <hip/hip_runtime.h>

// GrangerNet: 26 tiny MLPs (39 -> 32 -> 1), B = 131072, fp32.
// Mapping: lane = row (32 batch rows/block) + 32*h_half. Each lane accumulates
// 16 of the 32 hidden units for its row. Weights are per-lane-DIVERGENT
// (hh*16 float offset) -> real vector global loads, pipelined via vmcnt
// (no SMEM, no lgkmcnt(0) mixing in the hot loop). x_eff gather from LDS:
// one ds_read_b32 serves all 32 rows (2-way broadcast across halves = free).
// TB=32 -> LDS 63.2 KB < 64 KB -> 2 blocks/CU -> 16 waves/CU (4/SIMD).

#define LAG      20
#define NEFF     26
#define HID      32
#define TB       32                  // batch rows per block
#define NTHREADS 512                 // 8 waves
#define NBATCH   131072
#define XROW     494                 // 19*26 floats per x_eff row

#define TILE_F4  (TB * XROW / 4)     // 3952 float4 = 63,232 B

extern "C" __global__ void __launch_bounds__(NTHREADS, 4)
granger_kernel(const float* __restrict__ x_exp,
               const float* __restrict__ x_eff,
               const float* __restrict__ W1,
               const float* __restrict__ b1,
               const float* __restrict__ W2,
               const float* __restrict__ b2,
               float* __restrict__ out)
{
    __shared__ float xs[TB * XROW];          // 63,232 B (static, < 64 KiB)
    const int tid  = threadIdx.x;
    const int b0   = blockIdx.x * TB;

    // ---- stage x_eff tile into LDS: flat contiguous coalesced float4 copy ----
    {
        const float4* __restrict__ src =
            reinterpret_cast<const float4*>(x_eff + (size_t)b0 * XROW);
        float4* __restrict__ dst = reinterpret_cast<float4*>(xs);
#pragma unroll
        for (int j = 0; j < 8; ++j) {            // 8*512 = 4096 >= 3952
            int slot = tid + j * NTHREADS;
            if (slot < TILE_F4) dst[slot] = src[slot];
        }
    }

    const int lane = tid & 63;
    const int row  = lane & 31;                  // batch row within tile
    const int hh   = lane >> 5;                  // hidden half: 0 -> h 0..15, 1 -> h 16..31
    const int w    = tid >> 6;                   // wave 0..7

    // ---- per-lane x_exp (20 floats) straight from global (tiny, L2-friendly) ----
    float xe[LAG];
    {
        const float4* __restrict__ xsrc =
            reinterpret_cast<const float4*>(x_exp + (size_t)(b0 + row) * LAG);
#pragma unroll
        for (int j = 0; j < LAG / 4; ++j) {
            float4 v = xsrc[j];
            xe[4*j+0] = v.x; xe[4*j+1] = v.y; xe[4*j+2] = v.z; xe[4*j+3] = v.w;
        }
    }
    __syncthreads();

    const float* __restrict__ xr = xs + row * XROW;   // this lane's x_eff row

#pragma unroll 1
    for (int k = 0; k < 4; ++k) {
        const int f = 8 * k + w;                 // waves 0,1: 4 effects; others: 3
        if (f >= NEFF) break;                    // wave-uniform

        // per-lane weight base: half 'hh' of effect f's W1 (divergent -> vector loads)
        const float4* __restrict__ w1p =
            reinterpret_cast<const float4*>(W1 + (size_t)f * (39 * HID) + hh * 16);
        const float4* __restrict__ b1p =
            reinterpret_cast<const float4*>(b1 + f * HID + hh * 16);
        const float4* __restrict__ w2p =
            reinterpret_cast<const float4*>(W2 + f * HID + hh * 16);

        const float bias2 = b2[f];               // hoisted: wait resolves early

        float acc[16];
#pragma unroll
        for (int q = 0; q < 4; ++q) {
            float4 bv = b1p[q];
            acc[4*q+0] = bv.x; acc[4*q+1] = bv.y; acc[4*q+2] = bv.z; acc[4*q+3] = bv.w;
        }

        // x_cat[0..18] = x_eff[b][i][f]: LDS gather, one b32 per i serves all rows
#pragma unroll
        for (int i = 0; i < LAG - 1; ++i) {
            const float x = xr[i * NEFF + f];
#pragma unroll
            for (int q = 0; q < 4; ++q) {
                float4 wv = w1p[i * 8 + q];      // row i, this half's 16 weights
                acc[4*q+0] = fmaf(x, wv.x, acc[4*q+0]);
                acc[4*q+1] = fmaf(x, wv.y, acc[4*q+1]);
                acc[4*q+2] = fmaf(x, wv.z, acc[4*q+2]);
                acc[4*q+3] = fmaf(x, wv.w, acc[4*q+3]);
            }
        }
        // x_cat[19..38] = x_exp[b][0..19]: registers
#pragma unroll
        for (int j = 0; j < LAG; ++j) {
            const float x = xe[j];
#pragma unroll
            for (int q = 0; q < 4; ++q) {
                float4 wv = w1p[(LAG - 1 + j) * 8 + q];
                acc[4*q+0] = fmaf(x, wv.x, acc[4*q+0]);
                acc[4*q+1] = fmaf(x, wv.y, acc[4*q+1]);
                acc[4*q+2] = fmaf(x, wv.z, acc[4*q+2]);
                acc[4*q+3] = fmaf(x, wv.w, acc[4*q+3]);
            }
        }

        // layer 2: relu + dot over this half's 16 hidden units
        float p = 0.0f;
#pragma unroll
        for (int q = 0; q < 4; ++q) {
            float4 wv = w2p[q];
            p = fmaf(fmaxf(acc[4*q+0], 0.0f), wv.x, p);
            p = fmaf(fmaxf(acc[4*q+1], 0.0f), wv.y, p);
            p = fmaf(fmaxf(acc[4*q+2], 0.0f), wv.z, p);
            p = fmaf(fmaxf(acc[4*q+3], 0.0f), wv.w, p);
        }
        p += __shfl_xor(p, 32, 64);              // combine the two hidden halves
        p += bias2;

        if (hh == 0)
            out[(size_t)(b0 + row) * NEFF + f] = p;
    }
}

extern "C" void kernel_launch(void* const* d_in, const int* in_sizes, int n_in,
                              void* d_out, int out_size, void* d_ws, size_t ws_size,
                              hipStream_t stream)
{
    const float* x_exp = (const float*)d_in[0];
    const float* x_eff = (const float*)d_in[1];
    const float* W1    = (const float*)d_in[2];
    const float* b1    = (const float*)d_in[3];
    const float* W2    = (const float*)d_in[4];
    const float* b2    = (const float*)d_in[5];
    float* out = (float*)d_out;

    const int grid = NBATCH / TB;                // 4096 blocks, no tail
    granger_kernel<<<grid, NTHREADS, 0, stream>>>(
        x_exp, x_eff, W1, b1, W2, b2, out);
}

// Round 9
// 546.350 us; speedup vs baseline: 1.5527x; 1.5527x over previous
//
#include <hip/hip_runtime.h>

// GrangerNet: 26 tiny MLPs (39 -> 32 -> 1), B = 131072, fp32.
// lane = batch row (LDS-optimal x delivery: 64 unique floats per ds_read).
// Weights wave-uniform -> s_load_dwordx16 -> SGPR FMA operands (16 FMA/load).
// All 39 x-values hoisted to VGPRs BEFORE the FMA body: one lgkmcnt drain,
// then the body has only SMEM on lgkmcnt -> precise counted waits, deep
// s_load pipelining (SMEM+DS share lgkmcnt and SMEM is out-of-order; mixing
// them per-iteration forces lgkmcnt(0) drains -- r3's suspected 24% VALUBusy).
// 1024 threads = 16 waves = 4 waves/SIMD at 1 block/CU (139.5 KB LDS).
// Eff tile padded 494->497 (coprime 32): 2-way banks. Out staged+coalesced.

#define LAG      20
#define NEFF     26
#define HID      32
#define TB       64
#define NTHREADS 1024
#define NBATCH   131072
#define XROW     494                 // 19*26 payload floats per row
#define EFF_STRIDE 497               // padded row (497 mod 32 = 17, coprime)
#define EXP_STRIDE 21                // 20 + 1 pad
#define OUT_STRIDE 27                // 26 + 1 pad

#define EFF_FLOATS (TB * EFF_STRIDE)            // 31808
#define EXP_OFF    EFF_FLOATS
#define EXP_FLOATS (TB * EXP_STRIDE)            // 1344
#define OUT_OFF    (EXP_OFF + EXP_FLOATS)       // 33152
#define OUT_FLOATS (TB * OUT_STRIDE)            // 1728
#define LDS_FLOATS (OUT_OFF + OUT_FLOATS)       // 34880
#define LDS_BYTES  (LDS_FLOATS * 4)             // 139,520 B <= 160 KiB

extern "C" __global__ void __launch_bounds__(NTHREADS, 4)
granger_kernel(const float* __restrict__ x_exp,
               const float* __restrict__ x_eff,
               const float* __restrict__ W1,
               const float* __restrict__ b1,
               const float* __restrict__ W2,
               const float* __restrict__ b2,
               float* __restrict__ out)
{
    extern __shared__ float lds[];
    const int tid = threadIdx.x;
    const int b0  = blockIdx.x * TB;

    // ---- stage x_eff tile: coalesced b32, identical linear order, row-padded ----
    {
        const float* __restrict__ src = x_eff + (size_t)b0 * XROW;
#pragma unroll
        for (int k = 0; k < 31; ++k) {               // 31*1024 = 31744 >= 31616
            int e = tid + k * NTHREADS;
            if (e < TB * XROW) {
                int r = e / XROW;                    // magic-mul
                int c = e - r * XROW;
                lds[r * EFF_STRIDE + c] = src[e];
            }
        }
    }
    // ---- stage x_exp tile (64 x 20 -> stride 21) ----
    {
        const float* __restrict__ src = x_exp + (size_t)b0 * LAG;
#pragma unroll
        for (int k = 0; k < 2; ++k) {
            int e = tid + k * NTHREADS;
            if (e < TB * LAG) {
                int r = e / LAG;
                int j = e - r * LAG;
                lds[EXP_OFF + r * EXP_STRIDE + j] = src[e];
            }
        }
    }
    __syncthreads();

    const int lane = tid & 63;                        // batch row within tile
    const int w    = __builtin_amdgcn_readfirstlane(tid >> 6);   // wave 0..15

    const float* __restrict__ effp = lds + lane * EFF_STRIDE;
    const float* __restrict__ expp = lds + EXP_OFF + lane * EXP_STRIDE;

#pragma unroll 1
    for (int k = 0; k < 2; ++k) {
        const int f = w + 16 * k;                     // waves 0..9: 2 effects; 10..15: 1
        if (f >= NEFF) break;                         // wave-uniform

        const float* __restrict__ w1f = W1 + f * (39 * HID);
        const float* __restrict__ b1f = b1 + f * HID;
        const float* __restrict__ w2f = W2 + f * HID;
        const float* __restrict__ xf  = effp + f;     // per-lane base, + i*26 imm

        // ---- hoist all 39 x_cat values into VGPRs (pure ds_read burst) ----
        float xv[39];
#pragma unroll
        for (int i = 0; i < 19; ++i) xv[i] = xf[i * NEFF];
#pragma unroll
        for (int j = 0; j < LAG; ++j) xv[19 + j] = expp[j];

        float acc[HID];
#pragma unroll
        for (int h = 0; h < HID; ++h) acc[h] = b1f[h];    // uniform -> s_load

        // ---- FMA body: only SMEM on lgkmcnt -> precise counted waits ----
#pragma unroll
        for (int i = 0; i < 39; ++i) {
            const float x = xv[i];
#pragma unroll
            for (int h = 0; h < HID; ++h)
                acc[h] = fmaf(x, w1f[i * HID + h], acc[h]);   // SGPR weight
        }

        // layer 2: relu + dot (SGPR weights)
        float p = b2[f];
#pragma unroll
        for (int h = 0; h < HID; ++h)
            p = fmaf(fmaxf(acc[h], 0.0f), w2f[h], p);

        lds[OUT_OFF + lane * OUT_STRIDE + f] = p;     // 2-way banks (27 coprime 32)
    }
    __syncthreads();

    // ---- coalesced output flush ----
    {
        float* __restrict__ ob = out + (size_t)b0 * NEFF;
#pragma unroll
        for (int k = 0; k < 2; ++k) {
            int o = tid + k * NTHREADS;
            if (o < TB * NEFF) {
                int r  = o / NEFF;
                int fo = o - r * NEFF;
                ob[o] = lds[OUT_OFF + r * OUT_STRIDE + fo];
            }
        }
    }
}

extern "C" void kernel_launch(void* const* d_in, const int* in_sizes, int n_in,
                              void* d_out, int out_size, void* d_ws, size_t ws_size,
                              hipStream_t stream)
{
    const float* x_exp = (const float*)d_in[0];
    const float* x_eff = (const float*)d_in[1];
    const float* W1    = (const float*)d_in[2];
    const float* b1    = (const float*)d_in[3];
    const float* W2    = (const float*)d_in[4];
    const float* b2    = (const float*)d_in[5];
    float* out = (float*)d_out;

    // >64 KiB dynamic LDS opt-in (host-side, graph-capture safe, idempotent)
    hipFuncSetAttribute(reinterpret_cast<const void*>(granger_kernel),
                        hipFuncAttributeMaxDynamicSharedMemorySize, LDS_BYTES);

    const int grid = NBATCH / TB;                    // 2048 blocks
    granger_kernel<<<grid, NTHREADS, LDS_BYTES, stream>>>(
        x_exp, x_eff, W1, b1, W2, b2, out);
}